// Round 1
// baseline (382.435 us; speedup 1.0000x reference)
//
#include <hip/hip_runtime.h>
#include <math.h>

#define N_NODES 16384
#define N_EDGES 131072
#define INV_SQRT3 0.57735026918962576451f
#define INV_SQRT2 0.70710678118654752440f
#define LN_EPS 1e-5f

__device__ __forceinline__ float wave_sum(float v) {
    #pragma unroll
    for (int off = 32; off > 0; off >>= 1) v += __shfl_xor(v, off, 64);
    return v;
}

// 4-byte-aligned 12-byte vector (HIP float3 may claim 16B alignment; this one is safe
// for the x[128+3u] / out[...+3u] addresses which are only 4B aligned).
struct __attribute__((packed, aligned(4))) f3 { float x, y, z; };

// ---------------- CSR build ----------------

__global__ __launch_bounds__(256) void hist_kernel(
    const int* __restrict__ edst, int* __restrict__ counts)
{
    const int e = blockIdx.x * 256 + threadIdx.x;
    if (e < N_EDGES) atomicAdd(&counts[edst[e]], 1);
}

// Single block, 1024 threads, 16 counters each: exclusive scan -> row_ptr, cursor.
__global__ __launch_bounds__(1024) void scan_kernel(
    const int* __restrict__ counts, int* __restrict__ row_ptr,
    int* __restrict__ cursor)
{
    __shared__ int lds[1024];
    const int t = threadIdx.x;
    const int base = t * 16;
    int local[16];
    int sum = 0;
    #pragma unroll
    for (int i = 0; i < 16; ++i) { local[i] = counts[base + i]; sum += local[i]; }
    lds[t] = sum;
    __syncthreads();
    for (int off = 1; off < 1024; off <<= 1) {
        int v = (t >= off) ? lds[t - off] : 0;
        __syncthreads();
        lds[t] += v;
        __syncthreads();
    }
    int run = (t == 0) ? 0 : lds[t - 1];
    #pragma unroll
    for (int i = 0; i < 16; ++i) {
        row_ptr[base + i] = run;
        cursor[base + i]  = run;
        run += local[i];
    }
    if (t == 1023) row_ptr[N_NODES] = run;   // == N_EDGES
}

// Store (edge_id, src) pairs so the hot loop has one fewer dependent load level.
__global__ __launch_bounds__(256) void fill_kernel(
    const int* __restrict__ edst, const int* __restrict__ esrc,
    int* __restrict__ cursor, int2* __restrict__ pairs)
{
    const int e = blockIdx.x * 256 + threadIdx.x;
    if (e < N_EDGES) {
        const int pos = atomicAdd(&cursor[edst[e]], 1);
        pairs[pos] = make_int2(e, esrc[e]);
    }
}

// ---------------- Fused gather + depthwise TP + bias + equivariant LN ----------------
// One wave per node. Lane u owns channels u and u+64 (mul=128 fields), channel u
// (mul=64 fields). All 960 outputs live in registers; output row written once.
//
// Hot-loop structure (this round):
//  - row_ptr bounds readfirstlane'd ONCE -> loop counter j is uniform ->
//    pairs[j] and sh[4e] become scalar (SMEM) loads, 2 fewer VMEM/edge.
//  - x vector part loaded as one dwordx3 instead of 3 scalar loads.
//  - 2-edge unroll: both edges' loads issued before either compute (2x MLP).
__global__ __launch_bounds__(256, 4) void gather_tp_ln_kernel(
    const float* __restrict__ nf,     // (N,320)
    const float* __restrict__ sh,     // (E,4)
    const float* __restrict__ w,      // (E,448)
    const float* __restrict__ bias,   // (192,)
    const int*   __restrict__ row_ptr,// (N+1,)
    const int2*  __restrict__ pairs,  // (E,) (edge_id, src)
    const float* __restrict__ lnw,    // (448,)
    const float* __restrict__ lnb,    // (192,)
    float* __restrict__ out)          // (N,960)
{
    const int n = blockIdx.x * 4 + (threadIdx.x >> 6);
    const int u = threadIdx.x & 63;
    if (n >= N_NODES) return;

    // wave-uniform loop bounds -> SGPRs; everything derived (j, pair addr, sh addr)
    // stays uniform so the compiler can scalarize those loads.
    const int start = __builtin_amdgcn_readfirstlane(row_ptr[n]);
    const int end   = __builtin_amdgcn_readfirstlane(row_ptr[n + 1]);

    float o0a0 = 0.f, o0a1 = 0.f, o0b = 0.f;
    float o1a0x = 0.f, o1a0y = 0.f, o1a0z = 0.f;   // field2, channel u
    float o1a1x = 0.f, o1a1y = 0.f, o1a1z = 0.f;   // field2, channel 64+u
    float o1bx = 0.f, o1by = 0.f, o1bz = 0.f;      // field3
    float o1cx = 0.f, o1cy = 0.f, o1cz = 0.f;      // field4

    int j = start;
    for (; j + 2 <= end; j += 2) {
        const int2 pA = pairs[j];
        const int2 pB = pairs[j + 1];
        const int eA = __builtin_amdgcn_readfirstlane(pA.x);
        const int sA = __builtin_amdgcn_readfirstlane(pA.y);
        const int eB = __builtin_amdgcn_readfirstlane(pB.x);
        const int sB = __builtin_amdgcn_readfirstlane(pB.y);

        // ---- issue ALL loads for both edges first (MLP x2) ----
        const float4 shA = *(const float4*)(sh + 4 * (size_t)eA);
        const float4 shB = *(const float4*)(sh + 4 * (size_t)eB);

        const float* __restrict__ xA = nf + (size_t)sA * 320;
        const float* __restrict__ xB = nf + (size_t)sB * 320;
        const float* __restrict__ wA = w  + (size_t)eA * 448;
        const float* __restrict__ wB = w  + (size_t)eB * 448;

        const float xsA0 = xA[u];
        const float xsA1 = xA[64 + u];
        const f3    avA  = *(const f3*)(xA + 128 + 3 * u);
        const float xsB0 = xB[u];
        const float xsB1 = xB[64 + u];
        const f3    avB  = *(const f3*)(xB + 128 + 3 * u);

        // edge_weight streams once (235 MB): non-temporal so it doesn't
        // evict the node_feat working set (21 MB, reused ~8x) from cache.
        const float wA0a = __builtin_nontemporal_load(&wA[u]);
        const float wA0b = __builtin_nontemporal_load(&wA[64 + u]);
        const float wA1a = __builtin_nontemporal_load(&wA[128 + u]);
        const float wA1b = __builtin_nontemporal_load(&wA[192 + u]);
        const float wA2  = __builtin_nontemporal_load(&wA[256 + u]);
        const float wA3  = __builtin_nontemporal_load(&wA[320 + u]);
        const float wA4  = __builtin_nontemporal_load(&wA[384 + u]);

        const float wB0a = __builtin_nontemporal_load(&wB[u]);
        const float wB0b = __builtin_nontemporal_load(&wB[64 + u]);
        const float wB1a = __builtin_nontemporal_load(&wB[128 + u]);
        const float wB1b = __builtin_nontemporal_load(&wB[192 + u]);
        const float wB2  = __builtin_nontemporal_load(&wB[256 + u]);
        const float wB3  = __builtin_nontemporal_load(&wB[320 + u]);
        const float wB4  = __builtin_nontemporal_load(&wB[384 + u]);

        // ---- compute edge A ----
        {
            const float ys = shA.x, yv0 = shA.y, yv1 = shA.z, yv2 = shA.w;
            o0a0 += wA0a * xsA0 * ys;
            o0a1 += wA0b * xsA1 * ys;
            o0b  += wA3 * (avA.x * yv0 + avA.y * yv1 + avA.z * yv2) * INV_SQRT3;
            const float p0 = wA1a * xsA0;
            const float p1 = wA1b * xsA1;
            o1a0x += p0 * yv0; o1a0y += p0 * yv1; o1a0z += p0 * yv2;
            o1a1x += p1 * yv0; o1a1y += p1 * yv1; o1a1z += p1 * yv2;
            const float q = wA2 * ys;
            o1bx += q * avA.x; o1by += q * avA.y; o1bz += q * avA.z;
            const float r = wA4 * INV_SQRT2;
            o1cx += r * (avA.y * yv2 - avA.z * yv1);
            o1cy += r * (avA.z * yv0 - avA.x * yv2);
            o1cz += r * (avA.x * yv1 - avA.y * yv0);
        }
        // ---- compute edge B ----
        {
            const float ys = shB.x, yv0 = shB.y, yv1 = shB.z, yv2 = shB.w;
            o0a0 += wB0a * xsB0 * ys;
            o0a1 += wB0b * xsB1 * ys;
            o0b  += wB3 * (avB.x * yv0 + avB.y * yv1 + avB.z * yv2) * INV_SQRT3;
            const float p0 = wB1a * xsB0;
            const float p1 = wB1b * xsB1;
            o1a0x += p0 * yv0; o1a0y += p0 * yv1; o1a0z += p0 * yv2;
            o1a1x += p1 * yv0; o1a1y += p1 * yv1; o1a1z += p1 * yv2;
            const float q = wB2 * ys;
            o1bx += q * avB.x; o1by += q * avB.y; o1bz += q * avB.z;
            const float r = wB4 * INV_SQRT2;
            o1cx += r * (avB.y * yv2 - avB.z * yv1);
            o1cy += r * (avB.z * yv0 - avB.x * yv2);
            o1cz += r * (avB.x * yv1 - avB.y * yv0);
        }
    }
    if (j < end) {                                  // tail (odd degree)
        const int2 pA = pairs[j];
        const int e   = __builtin_amdgcn_readfirstlane(pA.x);
        const int src = __builtin_amdgcn_readfirstlane(pA.y);

        const float4 s4 = *(const float4*)(sh + 4 * (size_t)e);
        const float ys = s4.x, yv0 = s4.y, yv1 = s4.z, yv2 = s4.w;

        const float* __restrict__ x  = nf + (size_t)src * 320;
        const float* __restrict__ we = w  + (size_t)e   * 448;

        const float xs0 = x[u];
        const float xs1 = x[64 + u];
        const f3    av  = *(const f3*)(x + 128 + 3 * u);

        const float w0a = __builtin_nontemporal_load(&we[u]);
        const float w0b = __builtin_nontemporal_load(&we[64 + u]);
        const float w1a = __builtin_nontemporal_load(&we[128 + u]);
        const float w1b = __builtin_nontemporal_load(&we[192 + u]);
        const float w2  = __builtin_nontemporal_load(&we[256 + u]);
        const float w3  = __builtin_nontemporal_load(&we[320 + u]);
        const float w4  = __builtin_nontemporal_load(&we[384 + u]);

        o0a0 += w0a * xs0 * ys;
        o0a1 += w0b * xs1 * ys;
        o0b  += w3 * (av.x * yv0 + av.y * yv1 + av.z * yv2) * INV_SQRT3;
        const float p0 = w1a * xs0;
        const float p1 = w1b * xs1;
        o1a0x += p0 * yv0; o1a0y += p0 * yv1; o1a0z += p0 * yv2;
        o1a1x += p1 * yv0; o1a1y += p1 * yv1; o1a1z += p1 * yv2;
        const float q = w2 * ys;
        o1bx += q * av.x; o1by += q * av.y; o1bz += q * av.z;
        const float r = w4 * INV_SQRT2;
        o1cx += r * (av.y * yv2 - av.z * yv1);
        o1cy += r * (av.z * yv0 - av.x * yv2);
        o1cz += r * (av.x * yv1 - av.y * yv0);
    }

    // bias accumulated once per edge -> degree * bias
    const float deg = (float)(end - start);
    o0a0 += deg * bias[u];
    o0a1 += deg * bias[64 + u];
    o0b  += deg * bias[128 + u];

    float* __restrict__ o = out + (size_t)n * 960;

    // ---- Field 0: mul=128, l=0 ----
    {
        const float s    = wave_sum(o0a0 + o0a1);
        const float ssq  = wave_sum(o0a0 * o0a0 + o0a1 * o0a1);
        const float mean = s * (1.0f / 128.0f);
        const float var  = ssq * (1.0f / 128.0f) - mean * mean;
        const float fn   = rsqrtf(var + LN_EPS);
        o[u]      = (o0a0 - mean) * fn * lnw[u]      + lnb[u];
        o[64 + u] = (o0a1 - mean) * fn * lnw[64 + u] + lnb[64 + u];
    }
    // ---- Field 1: mul=64, l=0 ----
    {
        const float s    = wave_sum(o0b);
        const float ssq  = wave_sum(o0b * o0b);
        const float mean = s * (1.0f / 64.0f);
        const float var  = ssq * (1.0f / 64.0f) - mean * mean;
        const float fn   = rsqrtf(var + LN_EPS);
        o[128 + u] = (o0b - mean) * fn * lnw[128 + u] + lnb[128 + u];
    }
    // ---- Field 2: mul=128, l=1 ----
    {
        const float ssq = wave_sum(o1a0x*o1a0x + o1a0y*o1a0y + o1a0z*o1a0z +
                                   o1a1x*o1a1x + o1a1y*o1a1y + o1a1z*o1a1z);
        const float fn  = rsqrtf(ssq * (1.0f / 384.0f) + LN_EPS);
        const float g0  = fn * lnw[192 + u];
        const float g1  = fn * lnw[256 + u];
        f3 v0 = { o1a0x * g0, o1a0y * g0, o1a0z * g0 };
        f3 v1 = { o1a1x * g1, o1a1y * g1, o1a1z * g1 };
        *(f3*)(o + 192 + u * 3)        = v0;
        *(f3*)(o + 192 + (64 + u) * 3) = v1;
    }
    // ---- Field 3: mul=64, l=1 ----
    {
        const float ssq = wave_sum(o1bx*o1bx + o1by*o1by + o1bz*o1bz);
        const float fn  = rsqrtf(ssq * (1.0f / 192.0f) + LN_EPS);
        const float g   = fn * lnw[320 + u];
        f3 v = { o1bx * g, o1by * g, o1bz * g };
        *(f3*)(o + 576 + u * 3) = v;
    }
    // ---- Field 4: mul=64, l=1 ----
    {
        const float ssq = wave_sum(o1cx*o1cx + o1cy*o1cy + o1cz*o1cz);
        const float fn  = rsqrtf(ssq * (1.0f / 192.0f) + LN_EPS);
        const float g   = fn * lnw[384 + u];
        f3 v = { o1cx * g, o1cy * g, o1cz * g };
        *(f3*)(o + 768 + u * 3) = v;
    }
}

extern "C" void kernel_launch(void* const* d_in, const int* in_sizes, int n_in,
                              void* d_out, int out_size, void* d_ws, size_t ws_size,
                              hipStream_t stream) {
    const float* node_feat   = (const float*)d_in[0];
    const float* edge_sh     = (const float*)d_in[1];
    const float* edge_weight = (const float*)d_in[2];
    const float* tp_bias     = (const float*)d_in[3];
    const float* ln_weight   = (const float*)d_in[4];
    const float* ln_bias     = (const float*)d_in[5];
    const int*   edge_src    = (const int*)d_in[6];
    const int*   edge_dst    = (const int*)d_in[7];
    float* out = (float*)d_out;

    // workspace (ints): counts[16384] | row_ptr[16385] | cursor[16384] | pad | pairs[131072 int2]
    int* counts   = (int*)d_ws;
    int* row_ptr  = counts + N_NODES;
    int* cursor   = row_ptr + (N_NODES + 1);
    int2* pairs   = (int2*)(cursor + N_NODES + 1);   // 8B-aligned

    hipMemsetAsync(counts, 0, (size_t)N_NODES * sizeof(int), stream);

    hist_kernel<<<N_EDGES / 256, 256, 0, stream>>>(edge_dst, counts);
    scan_kernel<<<1, 1024, 0, stream>>>(counts, row_ptr, cursor);
    fill_kernel<<<N_EDGES / 256, 256, 0, stream>>>(edge_dst, edge_src, cursor, pairs);

    gather_tp_ln_kernel<<<N_NODES / 4, 256, 0, stream>>>(
        node_feat, edge_sh, edge_weight, tp_bias,
        row_ptr, pairs, ln_weight, ln_bias, out);
}